// Round 10
// baseline (1527.857 us; speedup 1.0000x reference)
//
#include <hip/hip_runtime.h>
#include <cstdint>
#include <cstddef>

// Problem constants (match reference: B=64, L=512, STEPS=20)
#define LDIM 512
#define BATCH 64
#define NSTEPS 20
#define NTHREADS 256
#define PTHREADS 512   // 8 waves/block
#define SLABS 8        // row slabs per batch (64 rows each)
#define HALVES 2       // column halves (256 cols each)
#define BPB 16         // blocks per batch = SLABS*HALVES
#define CNT_STRIDE 16  // 64 B per counter: no line sharing across batches

using f4 = __attribute__((ext_vector_type(4))) float;
using h4 = __attribute__((ext_vector_type(4))) _Float16;

#define MU_MASKED (-1024.0f)   // exact in fp16; sentinel for M==0
#define MU_THRESH (-512.0f)

__device__ __forceinline__ float relu_f(float x) { return fmaxf(x, 0.0f); }
__device__ __forceinline__ float sign_f(float x) {
  return (x > 0.0f) ? 1.0f : ((x < 0.0f) ? -1.0f : 0.0f);
}
__device__ __forceinline__ float wave_reduce_sum(float v) {
  v += __shfl_xor(v, 32);
  v += __shfl_xor(v, 16);
  v += __shfl_xor(v, 8);
  v += __shfl_xor(v, 4);
  v += __shfl_xor(v, 2);
  v += __shfl_xor(v, 1);
  return v;
}
// Agent-scope RELAXED accesses: sc1 ops serviced at the coherence point.
// Never acquire/threadfence (agent-acquire = full per-XCD L2 invalidate;
// round-1 spent 97% of its time there).
__device__ __forceinline__ void st_agent(float* p, float v) {
  __hip_atomic_store(p, v, __ATOMIC_RELAXED, __HIP_MEMORY_SCOPE_AGENT);
}
__device__ __forceinline__ float ld_agent(const float* p) {
  return __hip_atomic_load(p, __ATOMIC_RELAXED, __HIP_MEMORY_SCOPE_AGENT);
}

// ---------------------------------------------------------------------------
// k_build: MU[b][i][j] = M_ij ? fp16(0.5*(sc_ij + sc_ji) - s) : -1024, via
// 64x64 tile pairs (coalesced transpose through LDS). Also zeroes the
// per-batch sync counters. Grid: BATCH * 36 tile pairs; 256 threads.
// ---------------------------------------------------------------------------
__global__ __launch_bounds__(NTHREADS) void k_build(
    const float* __restrict__ scores, const float* __restrict__ M,
    const float* __restrict__ s_ptr, _Float16* __restrict__ MU,
    unsigned int* __restrict__ counter) {
  __shared__ float Sa[64][65];
  __shared__ float Sb[64][65];
  if (blockIdx.x < BATCH && threadIdx.x == 0) counter[blockIdx.x * CNT_STRIDE] = 0u;
  const int b = blockIdx.x / 36;
  int rem = blockIdx.x % 36;
  int ti = 0;
  while (rem >= 8 - ti) {
    rem -= 8 - ti;
    ti++;
  }
  const int tj = ti + rem;
  const int tid = threadIdx.x;
  const int c = tid & 63;
  const int r0 = tid >> 6;
  const float sval = s_ptr[0];
  const size_t mb = (size_t)b * LDIM * LDIM;
#pragma unroll
  for (int k = 0; k < 16; k++) {
    const int r = 4 * k + r0;
    Sa[r][c] = scores[mb + (size_t)(ti * 64 + r) * LDIM + tj * 64 + c];
    Sb[r][c] = scores[mb + (size_t)(tj * 64 + r) * LDIM + ti * 64 + c];
  }
  __syncthreads();
#pragma unroll
  for (int k = 0; k < 16; k++) {
    const int r = 4 * k + r0;
    const size_t idx_ij = mb + (size_t)(ti * 64 + r) * LDIM + tj * 64 + c;
    const float mij = M[idx_ij];
    const float us = 0.5f * (Sa[r][c] + Sb[c][r]) - sval;
    MU[idx_ij] = (_Float16)((mij != 0.0f) ? us : MU_MASKED);
    if (ti != tj) {
      const size_t idx_ji = mb + (size_t)(tj * 64 + r) * LDIM + ti * 64 + c;
      const float mji = M[idx_ji];
      const float usj = 0.5f * (Sb[r][c] + Sa[c][r]) - sval;
      MU[idx_ji] = (_Float16)((mji != 0.0f) ? usj : MU_MASKED);
    }
  }
}

// ---------------------------------------------------------------------------
// k_rho: rho fp32 -> fp16 (0.5 MB, L2-resident for the step loop).
// Precision: rho in [0,1); fp16 abs err <= ~5e-4; enters only as the
// soft-threshold rho*a_t (a_t <= 0.005) -> <=2.5e-6/step, negligible.
// ---------------------------------------------------------------------------
__global__ __launch_bounds__(NTHREADS) void k_rho(const float* __restrict__ rho,
                                                  _Float16* __restrict__ rho_h) {
  const int idx = (blockIdx.x * NTHREADS + threadIdx.x) * 4;
  const f4 v = *(const f4*)(rho + idx);
  h4 o;
#pragma unroll
  for (int k = 0; k < 4; k++) o[k] = (_Float16)v[k];
  *(h4*)(rho_h + idx) = o;
}

// ---------------------------------------------------------------------------
// k_persist (round 10): 512-THREAD BLOCKS FOR FULL RESIDENCY.
// Round 9's 74 KB/1024-thr blocks ran at ~47% occupancy (== round 5's known
// 1-block/CU signature): only 16 waves/CU, grid in 2 generations. This
// re-tile makes residency unambiguous: 1024 blocks x 512 thr, 38 KB LDS ->
// 4 blocks/CU = 2048 thr = 32 waves/CU (the HW thread cap).
// Block = (batch b, 64-row slab sb of 8, col-half hf of 2); blockIdx =
// b*16 + sb*2 + hf (adjacent siblings -> plain-launch drain-safe: any
// resident prefix is whole batches + at most one partial that completes as
// in-order dispatch refills freed slots).
// Per thread (8 waves x 64 lanes): 8 rows x 4 cols of A_hat in VGPRs
// (32 regs; __launch_bounds__(512,8) caps at 64 — round 9 proved this exact
// per-thread code compiles spill-free at 64).
// Per block LDS: MU fp16 [64][256] = 32 KB RESIDENT + stage 4 KB + lmsg 2 KB
// = 38 KB. rho fp16 streams from L2. Zero bulk global traffic in step loop.
// Cross-block: partials via sc1 relaxed atomics + per-batch monotonic
// arrival counter (16 arrivals/step). NO fences, NO acquire.
// ---------------------------------------------------------------------------
__global__ __launch_bounds__(PTHREADS, 8) void k_persist(
    const float* __restrict__ scores, const _Float16* __restrict__ MU,
    const _Float16* __restrict__ rho_h, const float* __restrict__ w_ptr,
    const float* __restrict__ alpha_ptr, const float* __restrict__ belt_ptr,
    const float* __restrict__ lra_ptr, const float* __restrict__ lrb_ptr,
    float* __restrict__ rowpart, float* __restrict__ colpart,
    unsigned int* __restrict__ counter, float* __restrict__ Ah) {
  __shared__ _Float16 muL[64][256];  // 32 KB: resident masked usym tile
  __shared__ float stage[4][256];    // 4 KB: cross-wave col-sum staging
  __shared__ float lmsgS[LDIM];      // 2 KB  (total 38 KB -> 4 blocks/CU)

  const int tid = threadIdx.x;
  const int lane = tid & 63;
  const int w = tid >> 6;               // 0..7
  const int b = blockIdx.x >> 4;        // batch
  const int s = blockIdx.x & 15;
  const int sb = s >> 1;                // row slab 0..7 (64 rows)
  const int hf = s & 1;                 // col half 0..1
  const int wrow = sb * 64 + w * 8;     // global first row of this wave
  const int j0 = lane << 2;             // local col 0..255 (step 4)
  const int gj0 = hf * 256 + j0;        // global col
  const size_t mb = (size_t)b * LDIM * LDIM;

  const float wv = w_ptr[0];
  const float belt = belt_ptr[0];
  const float lra = lra_ptr[0];
  const float lrb = lrb_ptr[0];
  float at = alpha_ptr[0];  // a_t = alpha * lra^sp
  float lrbp = 1.0f;        // lrb^(sp-1) for sp>=1
  float lm_reg = 0.0f;      // Lm[tid] (valid for tid < LDIM)

  const size_t RP = (size_t)BATCH * HALVES * LDIM;  // rowpart parity stride
  const size_t CP = (size_t)BATCH * SLABS * LDIM;   // colpart parity stride
  unsigned int* const cnt = counter + b * CNT_STRIDE;

  f4 ahv[8];
  float colacc[4];

  // __syncthreads() drains vmcnt per wave -> all sc1 partial stores are at
  // the coherence point before tid0's counter add. Spin load RELAXED.
#define ARRIVE_WAIT(tgt)                                                       \
  do {                                                                         \
    __syncthreads();                                                           \
    if (tid == 0) {                                                            \
      __hip_atomic_fetch_add(cnt, 1u, __ATOMIC_RELEASE,                        \
                             __HIP_MEMORY_SCOPE_AGENT);                        \
      while (__hip_atomic_load(cnt, __ATOMIC_RELAXED,                          \
                               __HIP_MEMORY_SCOPE_AGENT) < (tgt))              \
        __builtin_amdgcn_s_sleep(8);                                           \
    }                                                                          \
    __syncthreads();                                                           \
  } while (0)

#define COLREDUCE_STORE(dstp)                                                  \
  do {                                                                         \
    if (w < 4) {                                                               \
      f4 sa = {colacc[0], colacc[1], colacc[2], colacc[3]};                    \
      *(f4*)&stage[w][j0] = sa;                                                \
    }                                                                          \
    __syncthreads();                                                           \
    if (w >= 4) {                                                              \
      f4 sa = *(f4*)&stage[w - 4][j0];                                         \
      sa[0] += colacc[0]; sa[1] += colacc[1];                                  \
      sa[2] += colacc[2]; sa[3] += colacc[3];                                  \
      *(f4*)&stage[w - 4][j0] = sa;                                            \
    }                                                                          \
    __syncthreads();                                                           \
    if (tid < 256) {                                                           \
      float cs = stage[0][tid] + stage[1][tid] + stage[2][tid] +               \
                 stage[3][tid];                                                \
      st_agent((dstp) + tid, cs);                                              \
    }                                                                          \
  } while (0)

  // ---- P_init: A_hat_0 = scores into VGPRs; MU(fp16) into LDS; partials ----
#pragma unroll
  for (int k = 0; k < 4; k++) colacc[k] = 0.0f;
#pragma unroll
  for (int r = 0; r < 8; r++) {
    const int i = wrow + r;
    const size_t base = mb + (size_t)i * LDIM + gj0;
    const f4 s0 = *(const f4*)(scores + base);
    const h4 m0 = *(const h4*)(MU + base);
    ahv[r] = s0;
    *(h4*)&muL[(w << 3) + r][j0] = m0;
    float rowc = 0.0f;
#pragma unroll
    for (int k = 0; k < 4; k++) {
      const float c0v = ((float)m0[k] > MU_THRESH) ? s0[k] : 0.0f;
      rowc += c0v;
      colacc[k] += c0v;
    }
    const float rhalf = wave_reduce_sum(rowc);
    if (lane == 0)
      st_agent(rowpart + ((size_t)b * HALVES + hf) * LDIM + i, rhalf);
  }
  COLREDUCE_STORE(colpart + ((size_t)b * SLABS + sb) * LDIM + hf * 256);
  ARRIVE_WAIT((unsigned)BPB);

  // ---- 20 steps ----
  for (int sp = 0; sp < NSTEPS; ++sp) {
    const int par = sp & 1;
    // lm phase: identical on all 16 sibling blocks (bit-deterministic).
    {
      const int i = tid;  // PTHREADS == 512 == LDIM: every thread owns a row
      const float rsum =
          ld_agent(rowpart + (size_t)par * RP + ((size_t)b * HALVES + 0) * LDIM + i) +
          ld_agent(rowpart + (size_t)par * RP + ((size_t)b * HALVES + 1) * LDIM + i);
      const float* cb = colpart + (size_t)par * CP + (size_t)b * SLABS * LDIM + i;
      float csum = 0.0f;
#pragma unroll
      for (int s2 = 0; s2 < SLABS; s2++) csum += ld_agent(cb + (size_t)s2 * LDIM);
      const float rd = 0.5f * (rsum + csum) - 1.0f;
      float lm;
      if (sp == 0)
        lm = wv * relu_f(rd);
      else
        lm = lm_reg + belt * lrbp * relu_f(rd);
      lm_reg = lm;
      lmsgS[i] = lm * sign_f(rd);
    }
    __syncthreads();

    const f4 lmja = *(const f4*)&lmsgS[gj0];
    const bool last = (sp == NSTEPS - 1);
    const float rat = at;
#pragma unroll
    for (int k = 0; k < 4; k++) colacc[k] = 0.0f;

#pragma unroll
    for (int r = 0; r < 8; r++) {
      const int i = wrow + r;
      const int lr = (w << 3) + r;
      const float lmi = lmsgS[i];
      const h4 mh = *(const h4*)&muL[lr][j0];
      const h4 rh = *(const h4*)(rho_h + (size_t)i * LDIM + gj0);
      float rowc = 0.0f;
#pragma unroll
      for (int k = 0; k < 4; k++) {
        const float mv = (float)mh[k];
        const bool ma = mv > MU_THRESH;
        const float g = ma ? (mv - lmi - lmja[k]) : 0.0f;
        const float u = ahv[r][k] * fmaf(rat, g, 1.0f);
        const float v = fminf(relu_f(fabsf(u) - (float)rh[k] * rat), 1.0f);
        ahv[r][k] = v;
        const float c = ma ? v : 0.0f;
        rowc += c;
        colacc[k] += c;
      }
      if (!last) {
        const float rhalf = wave_reduce_sum(rowc);
        if (lane == 0)
          st_agent(rowpart + (size_t)(par ^ 1) * RP +
                       ((size_t)b * HALVES + hf) * LDIM + i,
                   rhalf);
      }
    }
    if (!last) {
      COLREDUCE_STORE(colpart + (size_t)(par ^ 1) * CP +
                      ((size_t)b * SLABS + sb) * LDIM + hf * 256);
      ARRIVE_WAIT((unsigned)BPB * (unsigned)(sp + 2));
    }
    at *= lra;
    if (sp > 0) lrbp *= lrb;
  }

  // ---- write A_hat_20 out (k_final symmetrizes in place) ----
#pragma unroll
  for (int r = 0; r < 8; r++) {
    const size_t base = mb + (size_t)(wrow + r) * LDIM + gj0;
    *(f4*)(Ah + base) = ahv[r];
  }
#undef ARRIVE_WAIT
#undef COLREDUCE_STORE
}

// ---------------------------------------------------------------------------
// K_final: in-place A = 0.5*(Ah + Ah^T) .* M over tile pairs (64x64 tiles).
// ---------------------------------------------------------------------------
__global__ __launch_bounds__(NTHREADS) void k_final(float* __restrict__ Ah,
                                                    const float* __restrict__ M) {
  __shared__ float At[64][65];
  __shared__ float Bt[64][65];
  const int b = blockIdx.x / 36;
  int rem = blockIdx.x % 36;
  int ti = 0;
  while (rem >= 8 - ti) {
    rem -= 8 - ti;
    ti++;
  }
  const int tj = ti + rem;
  const int tid = threadIdx.x;
  const int c = tid & 63;
  const int r0 = tid >> 6;
  const size_t mb = (size_t)b * LDIM * LDIM;

#pragma unroll
  for (int k = 0; k < 16; k++) {
    const int r = 4 * k + r0;
    At[r][c] = Ah[mb + (size_t)(ti * 64 + r) * LDIM + tj * 64 + c];
    Bt[r][c] = Ah[mb + (size_t)(tj * 64 + r) * LDIM + ti * 64 + c];
  }
  __syncthreads();
#pragma unroll
  for (int k = 0; k < 16; k++) {
    const int r = 4 * k + r0;
    const size_t idx_ij = mb + (size_t)(ti * 64 + r) * LDIM + tj * 64 + c;
    const float mij = M[idx_ij];
    Ah[idx_ij] = 0.5f * (At[r][c] + Bt[c][r]) * mij;
    if (ti != tj) {
      const size_t idx_ji = mb + (size_t)(tj * 64 + r) * LDIM + ti * 64 + c;
      const float mji = M[idx_ji];
      Ah[idx_ji] = 0.5f * (Bt[r][c] + At[c][r]) * mji;
    }
  }
}

// ---------------------------------------------------------------------------
extern "C" void kernel_launch(void* const* d_in, const int* in_sizes, int n_in,
                              void* d_out, int out_size, void* d_ws,
                              size_t ws_size, hipStream_t stream) {
  const float* scores = (const float*)d_in[0];
  const float* M = (const float*)d_in[1];
  const float* s_p = (const float*)d_in[2];
  const float* w_p = (const float*)d_in[3];
  const float* rho = (const float*)d_in[4];
  const float* alpha_p = (const float*)d_in[5];
  const float* belt_p = (const float*)d_in[6];
  const float* lra_p = (const float*)d_in[7];
  const float* lrb_p = (const float*)d_in[8];
  float* Ah = (float*)d_out;

  char* ws = (char*)d_ws;
  size_t off = 0;
  auto walloc = [&](size_t bytes) -> void* {
    void* p = (void*)(ws + off);
    off += (bytes + 255) & ~(size_t)255;
    return p;
  };
  const size_t NEL = (size_t)BATCH * LDIM * LDIM;
  _Float16* MU = (_Float16*)walloc(NEL * 2);                               // 32 MB
  _Float16* rho_h = (_Float16*)walloc((size_t)LDIM * LDIM * 2);            // 0.5 MB
  float* rowpart = (float*)walloc((size_t)2 * BATCH * HALVES * LDIM * 4);  // 512 KB
  float* colpart = (float*)walloc((size_t)2 * BATCH * SLABS * LDIM * 4);   // 2 MB
  unsigned int* cnt = (unsigned int*)walloc(BATCH * CNT_STRIDE * 4);       // 4 KB
  (void)in_sizes;
  (void)n_in;
  (void)out_size;
  (void)ws_size;

  k_build<<<dim3(BATCH * 36), dim3(NTHREADS), 0, stream>>>(scores, M, s_p, MU,
                                                           cnt);
  k_rho<<<dim3(LDIM * LDIM / (NTHREADS * 4)), dim3(NTHREADS), 0, stream>>>(
      rho, rho_h);

  // Cooperative launch first (guaranteed co-residency of all 1024 blocks at
  // 4 blocks/CU); plain fallback is drain-safe via adjacent per-batch block
  // numbering + in-order dispatch (round-9-proven at 1-block/CU residency).
  void* args[] = {(void*)&scores,  (void*)&MU,      (void*)&rho_h,
                  (void*)&w_p,     (void*)&alpha_p, (void*)&belt_p,
                  (void*)&lra_p,   (void*)&lrb_p,   (void*)&rowpart,
                  (void*)&colpart, (void*)&cnt,     (void*)&Ah};
  hipError_t cerr = hipLaunchCooperativeKernel(
      (const void*)k_persist, dim3(BATCH * BPB), dim3(PTHREADS), args, 0,
      stream);
  if (cerr != hipSuccess) {
    k_persist<<<dim3(BATCH * BPB), dim3(PTHREADS), 0, stream>>>(
        scores, MU, rho_h, w_p, alpha_p, belt_p, lra_p, lrb_p, rowpart,
        colpart, cnt, Ah);
  }

  k_final<<<dim3(BATCH * 36), dim3(NTHREADS), 0, stream>>>(Ah, M);
}

// Round 11
// 734.000 us; speedup vs baseline: 2.0815x; 2.0815x over previous
//
#include <hip/hip_runtime.h>
#include <cstdint>
#include <cstddef>

// Problem constants (match reference: B=64, L=512, STEPS=20)
#define LDIM 512
#define BATCH 64
#define NSTEPS 20
#define NTHREADS 256
#define PTHREADS 512   // 8 waves/block
#define SLABS 8        // row slabs per batch (64 rows each)
#define HALVES 2       // column halves (256 cols each)
#define BPB 16         // blocks per batch = SLABS*HALVES
#define CNT_STRIDE 16  // 64 B per counter: no line sharing across batches

using f4 = __attribute__((ext_vector_type(4))) float;
using h4 = __attribute__((ext_vector_type(4))) _Float16;

#define MU_MASKED (-1024.0f)   // exact in fp16; sentinel for M==0
#define MU_THRESH (-512.0f)

__device__ __forceinline__ float relu_f(float x) { return fmaxf(x, 0.0f); }
__device__ __forceinline__ float sign_f(float x) {
  return (x > 0.0f) ? 1.0f : ((x < 0.0f) ? -1.0f : 0.0f);
}
__device__ __forceinline__ float wave_reduce_sum(float v) {
  v += __shfl_xor(v, 32);
  v += __shfl_xor(v, 16);
  v += __shfl_xor(v, 8);
  v += __shfl_xor(v, 4);
  v += __shfl_xor(v, 2);
  v += __shfl_xor(v, 1);
  return v;
}
// Agent-scope RELAXED accesses: sc1 ops serviced at the coherence point.
// Never acquire/threadfence (agent-acquire = full per-XCD L2 invalidate;
// round-1 spent 97% of its time there).
__device__ __forceinline__ void st_agent(float* p, float v) {
  __hip_atomic_store(p, v, __ATOMIC_RELAXED, __HIP_MEMORY_SCOPE_AGENT);
}
__device__ __forceinline__ float ld_agent(const float* p) {
  return __hip_atomic_load(p, __ATOMIC_RELAXED, __HIP_MEMORY_SCOPE_AGENT);
}

// ---------------------------------------------------------------------------
// k_build: MU[b][i][j] = M_ij ? fp16(0.5*(sc_ij + sc_ji) - s) : -1024, via
// 64x64 tile pairs (coalesced transpose through LDS). Also zeroes the
// per-batch sync counters. Grid: BATCH * 36 tile pairs; 256 threads.
// ---------------------------------------------------------------------------
__global__ __launch_bounds__(NTHREADS) void k_build(
    const float* __restrict__ scores, const float* __restrict__ M,
    const float* __restrict__ s_ptr, _Float16* __restrict__ MU,
    unsigned int* __restrict__ counter) {
  __shared__ float Sa[64][65];
  __shared__ float Sb[64][65];
  if (blockIdx.x < BATCH && threadIdx.x == 0) counter[blockIdx.x * CNT_STRIDE] = 0u;
  const int b = blockIdx.x / 36;
  int rem = blockIdx.x % 36;
  int ti = 0;
  while (rem >= 8 - ti) {
    rem -= 8 - ti;
    ti++;
  }
  const int tj = ti + rem;
  const int tid = threadIdx.x;
  const int c = tid & 63;
  const int r0 = tid >> 6;
  const float sval = s_ptr[0];
  const size_t mb = (size_t)b * LDIM * LDIM;
#pragma unroll
  for (int k = 0; k < 16; k++) {
    const int r = 4 * k + r0;
    Sa[r][c] = scores[mb + (size_t)(ti * 64 + r) * LDIM + tj * 64 + c];
    Sb[r][c] = scores[mb + (size_t)(tj * 64 + r) * LDIM + ti * 64 + c];
  }
  __syncthreads();
#pragma unroll
  for (int k = 0; k < 16; k++) {
    const int r = 4 * k + r0;
    const size_t idx_ij = mb + (size_t)(ti * 64 + r) * LDIM + tj * 64 + c;
    const float mij = M[idx_ij];
    const float us = 0.5f * (Sa[r][c] + Sb[c][r]) - sval;
    MU[idx_ij] = (_Float16)((mij != 0.0f) ? us : MU_MASKED);
    if (ti != tj) {
      const size_t idx_ji = mb + (size_t)(tj * 64 + r) * LDIM + ti * 64 + c;
      const float mji = M[idx_ji];
      const float usj = 0.5f * (Sb[r][c] + Sa[c][r]) - sval;
      MU[idx_ji] = (_Float16)((mji != 0.0f) ? usj : MU_MASKED);
    }
  }
}

// ---------------------------------------------------------------------------
// k_rho: rho fp32 -> fp16 (0.5 MB, L2-resident for the step loop).
// Precision: rho in [0,1); fp16 abs err <= ~5e-4; enters only as the
// soft-threshold rho*a_t (a_t <= 0.005) -> <=2.5e-6/step, negligible.
// ---------------------------------------------------------------------------
__global__ __launch_bounds__(NTHREADS) void k_rho(const float* __restrict__ rho,
                                                  _Float16* __restrict__ rho_h) {
  const int idx = (blockIdx.x * NTHREADS + threadIdx.x) * 4;
  const f4 v = *(const f4*)(rho + idx);
  h4 o;
#pragma unroll
  for (int k = 0; k < 4; k++) o[k] = (_Float16)v[k];
  *(h4*)(rho_h + idx) = o;
}

// ---------------------------------------------------------------------------
// k_persist (round 11): round-10 tiling with the CORRECT launch bounds.
// VGPR MODEL (settled by rounds 2-10): hipcc __launch_bounds__ 2nd arg is
// CUDA-style MIN BLOCKS PER CU. (512,8) demanded 64 waves/CU -> allocator
// crushed to 32 VGPRs -> ahv[8] spilled (round 10: 642 MB scratch writes).
// (512,4) = 4 blocks x 8 waves = 32 waves/CU = 8 waves/SIMD -> 64-VGPR
// budget, which this exact per-thread body compiled SPILL-FREE against in
// round 9.
// Tiling: 1024 blocks x 512 thr; block = (batch b, 64-row slab sb of 8,
// col-half hf of 2); blockIdx = b*16 + sb*2 + hf. LDS 38 KB -> 4 blocks/CU
// (152 KB), grid = exact capacity -> full residency; plain launch only
// (coop costs ~170 us/replay; plain drain-safe via adjacent per-batch
// numbering + in-order dispatch, proven rounds 6/9/10).
// Per thread: 8 rows x 4 cols of A_hat in VGPRs (32 regs). MU fp16
// [64][256] resident in LDS; rho fp16 from L2. Zero bulk global traffic in
// the step loop. Cross-block: sc1 relaxed partials + per-batch monotonic
// arrival counter (16 arrivals/step). NO fences, NO acquire.
// ---------------------------------------------------------------------------
__global__ __launch_bounds__(PTHREADS, 4) void k_persist(
    const float* __restrict__ scores, const _Float16* __restrict__ MU,
    const _Float16* __restrict__ rho_h, const float* __restrict__ w_ptr,
    const float* __restrict__ alpha_ptr, const float* __restrict__ belt_ptr,
    const float* __restrict__ lra_ptr, const float* __restrict__ lrb_ptr,
    float* __restrict__ rowpart, float* __restrict__ colpart,
    unsigned int* __restrict__ counter, float* __restrict__ Ah) {
  __shared__ _Float16 muL[64][256];  // 32 KB: resident masked usym tile
  __shared__ float stage[4][256];    // 4 KB: cross-wave col-sum staging
  __shared__ float lmsgS[LDIM];      // 2 KB  (total 38 KB -> 4 blocks/CU)

  const int tid = threadIdx.x;
  const int lane = tid & 63;
  const int w = tid >> 6;               // 0..7
  const int b = blockIdx.x >> 4;        // batch
  const int s = blockIdx.x & 15;
  const int sb = s >> 1;                // row slab 0..7 (64 rows)
  const int hf = s & 1;                 // col half 0..1
  const int wrow = sb * 64 + w * 8;     // global first row of this wave
  const int j0 = lane << 2;             // local col 0..255 (step 4)
  const int gj0 = hf * 256 + j0;        // global col
  const size_t mb = (size_t)b * LDIM * LDIM;

  const float wv = w_ptr[0];
  const float belt = belt_ptr[0];
  const float lra = lra_ptr[0];
  const float lrb = lrb_ptr[0];
  float at = alpha_ptr[0];  // a_t = alpha * lra^sp
  float lrbp = 1.0f;        // lrb^(sp-1) for sp>=1
  float lm_reg = 0.0f;      // Lm[tid] (valid for tid < LDIM)

  const size_t RP = (size_t)BATCH * HALVES * LDIM;  // rowpart parity stride
  const size_t CP = (size_t)BATCH * SLABS * LDIM;   // colpart parity stride
  unsigned int* const cnt = counter + b * CNT_STRIDE;

  f4 ahv[8];
  float colacc[4];

  // __syncthreads() drains vmcnt per wave -> all sc1 partial stores are at
  // the coherence point before tid0's counter add. Spin load RELAXED.
#define ARRIVE_WAIT(tgt)                                                       \
  do {                                                                         \
    __syncthreads();                                                           \
    if (tid == 0) {                                                            \
      __hip_atomic_fetch_add(cnt, 1u, __ATOMIC_RELEASE,                        \
                             __HIP_MEMORY_SCOPE_AGENT);                        \
      while (__hip_atomic_load(cnt, __ATOMIC_RELAXED,                          \
                               __HIP_MEMORY_SCOPE_AGENT) < (tgt))              \
        __builtin_amdgcn_s_sleep(8);                                           \
    }                                                                          \
    __syncthreads();                                                           \
  } while (0)

#define COLREDUCE_STORE(dstp)                                                  \
  do {                                                                         \
    if (w < 4) {                                                               \
      f4 sa = {colacc[0], colacc[1], colacc[2], colacc[3]};                    \
      *(f4*)&stage[w][j0] = sa;                                                \
    }                                                                          \
    __syncthreads();                                                           \
    if (w >= 4) {                                                              \
      f4 sa = *(f4*)&stage[w - 4][j0];                                         \
      sa[0] += colacc[0]; sa[1] += colacc[1];                                  \
      sa[2] += colacc[2]; sa[3] += colacc[3];                                  \
      *(f4*)&stage[w - 4][j0] = sa;                                            \
    }                                                                          \
    __syncthreads();                                                           \
    if (tid < 256) {                                                           \
      float cs = stage[0][tid] + stage[1][tid] + stage[2][tid] +               \
                 stage[3][tid];                                                \
      st_agent((dstp) + tid, cs);                                              \
    }                                                                          \
  } while (0)

  // ---- P_init: A_hat_0 = scores into VGPRs; MU(fp16) into LDS; partials ----
#pragma unroll
  for (int k = 0; k < 4; k++) colacc[k] = 0.0f;
#pragma unroll
  for (int r = 0; r < 8; r++) {
    const int i = wrow + r;
    const size_t base = mb + (size_t)i * LDIM + gj0;
    const f4 s0 = *(const f4*)(scores + base);
    const h4 m0 = *(const h4*)(MU + base);
    ahv[r] = s0;
    *(h4*)&muL[(w << 3) + r][j0] = m0;
    float rowc = 0.0f;
#pragma unroll
    for (int k = 0; k < 4; k++) {
      const float c0v = ((float)m0[k] > MU_THRESH) ? s0[k] : 0.0f;
      rowc += c0v;
      colacc[k] += c0v;
    }
    const float rhalf = wave_reduce_sum(rowc);
    if (lane == 0)
      st_agent(rowpart + ((size_t)b * HALVES + hf) * LDIM + i, rhalf);
  }
  COLREDUCE_STORE(colpart + ((size_t)b * SLABS + sb) * LDIM + hf * 256);
  ARRIVE_WAIT((unsigned)BPB);

  // ---- 20 steps ----
  for (int sp = 0; sp < NSTEPS; ++sp) {
    const int par = sp & 1;
    // lm phase: identical on all 16 sibling blocks (bit-deterministic).
    {
      const int i = tid;  // PTHREADS == 512 == LDIM: every thread owns a row
      const float rsum =
          ld_agent(rowpart + (size_t)par * RP + ((size_t)b * HALVES + 0) * LDIM + i) +
          ld_agent(rowpart + (size_t)par * RP + ((size_t)b * HALVES + 1) * LDIM + i);
      const float* cb = colpart + (size_t)par * CP + (size_t)b * SLABS * LDIM + i;
      float csum = 0.0f;
#pragma unroll
      for (int s2 = 0; s2 < SLABS; s2++) csum += ld_agent(cb + (size_t)s2 * LDIM);
      const float rd = 0.5f * (rsum + csum) - 1.0f;
      float lm;
      if (sp == 0)
        lm = wv * relu_f(rd);
      else
        lm = lm_reg + belt * lrbp * relu_f(rd);
      lm_reg = lm;
      lmsgS[i] = lm * sign_f(rd);
    }
    __syncthreads();

    const f4 lmja = *(const f4*)&lmsgS[gj0];
    const bool last = (sp == NSTEPS - 1);
    const float rat = at;
#pragma unroll
    for (int k = 0; k < 4; k++) colacc[k] = 0.0f;

#pragma unroll
    for (int r = 0; r < 8; r++) {
      const int i = wrow + r;
      const int lr = (w << 3) + r;
      const float lmi = lmsgS[i];
      const h4 mh = *(const h4*)&muL[lr][j0];
      const h4 rh = *(const h4*)(rho_h + (size_t)i * LDIM + gj0);
      float rowc = 0.0f;
#pragma unroll
      for (int k = 0; k < 4; k++) {
        const float mv = (float)mh[k];
        const bool ma = mv > MU_THRESH;
        const float g = ma ? (mv - lmi - lmja[k]) : 0.0f;
        const float u = ahv[r][k] * fmaf(rat, g, 1.0f);
        const float v = fminf(relu_f(fabsf(u) - (float)rh[k] * rat), 1.0f);
        ahv[r][k] = v;
        const float c = ma ? v : 0.0f;
        rowc += c;
        colacc[k] += c;
      }
      if (!last) {
        const float rhalf = wave_reduce_sum(rowc);
        if (lane == 0)
          st_agent(rowpart + (size_t)(par ^ 1) * RP +
                       ((size_t)b * HALVES + hf) * LDIM + i,
                   rhalf);
      }
    }
    if (!last) {
      COLREDUCE_STORE(colpart + (size_t)(par ^ 1) * CP +
                      ((size_t)b * SLABS + sb) * LDIM + hf * 256);
      ARRIVE_WAIT((unsigned)BPB * (unsigned)(sp + 2));
    }
    at *= lra;
    if (sp > 0) lrbp *= lrb;
  }

  // ---- write A_hat_20 out (k_final symmetrizes in place) ----
#pragma unroll
  for (int r = 0; r < 8; r++) {
    const size_t base = mb + (size_t)(wrow + r) * LDIM + gj0;
    *(f4*)(Ah + base) = ahv[r];
  }
#undef ARRIVE_WAIT
#undef COLREDUCE_STORE
}

// ---------------------------------------------------------------------------
// K_final: in-place A = 0.5*(Ah + Ah^T) .* M over tile pairs (64x64 tiles).
// ---------------------------------------------------------------------------
__global__ __launch_bounds__(NTHREADS) void k_final(float* __restrict__ Ah,
                                                    const float* __restrict__ M) {
  __shared__ float At[64][65];
  __shared__ float Bt[64][65];
  const int b = blockIdx.x / 36;
  int rem = blockIdx.x % 36;
  int ti = 0;
  while (rem >= 8 - ti) {
    rem -= 8 - ti;
    ti++;
  }
  const int tj = ti + rem;
  const int tid = threadIdx.x;
  const int c = tid & 63;
  const int r0 = tid >> 6;
  const size_t mb = (size_t)b * LDIM * LDIM;

#pragma unroll
  for (int k = 0; k < 16; k++) {
    const int r = 4 * k + r0;
    At[r][c] = Ah[mb + (size_t)(ti * 64 + r) * LDIM + tj * 64 + c];
    Bt[r][c] = Ah[mb + (size_t)(tj * 64 + r) * LDIM + ti * 64 + c];
  }
  __syncthreads();
#pragma unroll
  for (int k = 0; k < 16; k++) {
    const int r = 4 * k + r0;
    const size_t idx_ij = mb + (size_t)(ti * 64 + r) * LDIM + tj * 64 + c;
    const float mij = M[idx_ij];
    Ah[idx_ij] = 0.5f * (At[r][c] + Bt[c][r]) * mij;
    if (ti != tj) {
      const size_t idx_ji = mb + (size_t)(tj * 64 + r) * LDIM + ti * 64 + c;
      const float mji = M[idx_ji];
      Ah[idx_ji] = 0.5f * (Bt[r][c] + At[c][r]) * mji;
    }
  }
}

// ---------------------------------------------------------------------------
extern "C" void kernel_launch(void* const* d_in, const int* in_sizes, int n_in,
                              void* d_out, int out_size, void* d_ws,
                              size_t ws_size, hipStream_t stream) {
  const float* scores = (const float*)d_in[0];
  const float* M = (const float*)d_in[1];
  const float* s_p = (const float*)d_in[2];
  const float* w_p = (const float*)d_in[3];
  const float* rho = (const float*)d_in[4];
  const float* alpha_p = (const float*)d_in[5];
  const float* belt_p = (const float*)d_in[6];
  const float* lra_p = (const float*)d_in[7];
  const float* lrb_p = (const float*)d_in[8];
  float* Ah = (float*)d_out;

  char* ws = (char*)d_ws;
  size_t off = 0;
  auto walloc = [&](size_t bytes) -> void* {
    void* p = (void*)(ws + off);
    off += (bytes + 255) & ~(size_t)255;
    return p;
  };
  const size_t NEL = (size_t)BATCH * LDIM * LDIM;
  _Float16* MU = (_Float16*)walloc(NEL * 2);                               // 32 MB
  _Float16* rho_h = (_Float16*)walloc((size_t)LDIM * LDIM * 2);            // 0.5 MB
  float* rowpart = (float*)walloc((size_t)2 * BATCH * HALVES * LDIM * 4);  // 512 KB
  float* colpart = (float*)walloc((size_t)2 * BATCH * SLABS * LDIM * 4);   // 2 MB
  unsigned int* cnt = (unsigned int*)walloc(BATCH * CNT_STRIDE * 4);       // 4 KB
  (void)in_sizes;
  (void)n_in;
  (void)out_size;
  (void)ws_size;

  k_build<<<dim3(BATCH * 36), dim3(NTHREADS), 0, stream>>>(scores, M, s_p, MU,
                                                           cnt);
  k_rho<<<dim3(LDIM * LDIM / (NTHREADS * 4)), dim3(NTHREADS), 0, stream>>>(
      rho, rho_h);

  // Plain launch only (coop costs ~170 us/replay). 1024 blocks x 512 thr =
  // exact capacity at 4 blocks/CU (38 KB LDS, 64-VGPR budget via
  // __launch_bounds__(512,4)). Drain-safe at any occupancy via adjacent
  // per-batch block numbering + in-order dispatch (rounds 6/9/10).
  k_persist<<<dim3(BATCH * BPB), dim3(PTHREADS), 0, stream>>>(
      scores, MU, rho_h, w_p, alpha_p, belt_p, lra_p, lrb_p, rowpart, colpart,
      cnt, Ah);

  k_final<<<dim3(BATCH * 36), dim3(NTHREADS), 0, stream>>>(Ah, M);
}

// Round 12
// 542.316 us; speedup vs baseline: 2.8173x; 1.3535x over previous
//
#include <hip/hip_runtime.h>
#include <cstdint>
#include <cstddef>

// Problem constants (match reference: B=64, L=512, STEPS=20)
#define LDIM 512
#define BATCH 64
#define NSTEPS 20
#define NTHREADS 256
#define PTHREADS 512   // 8 waves/block
#define SLABS 8        // row slabs per batch (64 rows each); BPB == SLABS
#define BPB 8          // blocks per batch
#define CNT_STRIDE 16  // 64 B per counter: no line sharing across batches

using f4 = __attribute__((ext_vector_type(4))) float;
using h4 = __attribute__((ext_vector_type(4))) _Float16;

#define MU_MASKED (-1024.0f)   // exact in fp16; sentinel for M==0
#define MU_THRESH (-512.0f)

__device__ __forceinline__ float relu_f(float x) { return fmaxf(x, 0.0f); }
__device__ __forceinline__ float sign_f(float x) {
  return (x > 0.0f) ? 1.0f : ((x < 0.0f) ? -1.0f : 0.0f);
}
__device__ __forceinline__ float wave_reduce_sum(float v) {
  v += __shfl_xor(v, 32);
  v += __shfl_xor(v, 16);
  v += __shfl_xor(v, 8);
  v += __shfl_xor(v, 4);
  v += __shfl_xor(v, 2);
  v += __shfl_xor(v, 1);
  return v;
}
// Agent-scope RELAXED accesses: sc1 ops serviced at the coherence point.
// Never acquire/threadfence (agent-acquire = full per-XCD L2 invalidate;
// round-1 spent 97% of its time there).
__device__ __forceinline__ void st_agent(float* p, float v) {
  __hip_atomic_store(p, v, __ATOMIC_RELAXED, __HIP_MEMORY_SCOPE_AGENT);
}
__device__ __forceinline__ float ld_agent(const float* p) {
  return __hip_atomic_load(p, __ATOMIC_RELAXED, __HIP_MEMORY_SCOPE_AGENT);
}

// ---------------------------------------------------------------------------
// k_build: MU[b][i][j] = M_ij ? fp16(0.5*(sc_ij + sc_ji) - s) : -1024, via
// 64x64 tile pairs (coalesced transpose through LDS). Also zeroes the
// per-batch sync counters. Grid: BATCH * 36 tile pairs; 256 threads.
// ---------------------------------------------------------------------------
__global__ __launch_bounds__(NTHREADS) void k_build(
    const float* __restrict__ scores, const float* __restrict__ M,
    const float* __restrict__ s_ptr, _Float16* __restrict__ MU,
    unsigned int* __restrict__ counter) {
  __shared__ float Sa[64][65];
  __shared__ float Sb[64][65];
  if (blockIdx.x < BATCH && threadIdx.x == 0) counter[blockIdx.x * CNT_STRIDE] = 0u;
  const int b = blockIdx.x / 36;
  int rem = blockIdx.x % 36;
  int ti = 0;
  while (rem >= 8 - ti) {
    rem -= 8 - ti;
    ti++;
  }
  const int tj = ti + rem;
  const int tid = threadIdx.x;
  const int c = tid & 63;
  const int r0 = tid >> 6;
  const float sval = s_ptr[0];
  const size_t mb = (size_t)b * LDIM * LDIM;
#pragma unroll
  for (int k = 0; k < 16; k++) {
    const int r = 4 * k + r0;
    Sa[r][c] = scores[mb + (size_t)(ti * 64 + r) * LDIM + tj * 64 + c];
    Sb[r][c] = scores[mb + (size_t)(tj * 64 + r) * LDIM + ti * 64 + c];
  }
  __syncthreads();
#pragma unroll
  for (int k = 0; k < 16; k++) {
    const int r = 4 * k + r0;
    const size_t idx_ij = mb + (size_t)(ti * 64 + r) * LDIM + tj * 64 + c;
    const float mij = M[idx_ij];
    const float us = 0.5f * (Sa[r][c] + Sb[c][r]) - sval;
    MU[idx_ij] = (_Float16)((mij != 0.0f) ? us : MU_MASKED);
    if (ti != tj) {
      const size_t idx_ji = mb + (size_t)(tj * 64 + r) * LDIM + ti * 64 + c;
      const float mji = M[idx_ji];
      const float usj = 0.5f * (Sb[r][c] + Sa[c][r]) - sval;
      MU[idx_ji] = (_Float16)((mji != 0.0f) ? usj : MU_MASKED);
    }
  }
}

// ---------------------------------------------------------------------------
// k_rho: rho fp32 -> fp16 (0.5 MB, L2-resident for the step loop).
// ---------------------------------------------------------------------------
__global__ __launch_bounds__(NTHREADS) void k_rho(const float* __restrict__ rho,
                                                  _Float16* __restrict__ rho_h) {
  const int idx = (blockIdx.x * NTHREADS + threadIdx.x) * 4;
  const f4 v = *(const f4*)(rho + idx);
  h4 o;
#pragma unroll
  for (int k = 0; k < 4; k++) o[k] = (_Float16)v[k];
  *(h4*)(rho_h + idx) = o;
}

// ---------------------------------------------------------------------------
// k_persist (round 12): FULL-ROW blocks, single generation, 128-VGPR budget.
// VGPR LAW (fits all 5 observations r2-r11): budget = 256 / arg2 of
// __launch_bounds__ (or waves_per_eu), independent of block size.
//   (1024,4)->64, wpe(4,4)->64, wpe(8)->32, (512,8)->32, (512,4)->64.
// => (512,2) -> 128-VGPR budget: ahv[8][2] (64 state) + ~35 temps fits
// WITHOUT spill (the r3/r4 spills were this body at budget 64).
// Tiling: 512 blocks x 512 thr; block = (batch b, 64-row slab sb of 8) with
// FULL 512-col rows -> row sums are wave-local (no cross-block row halves).
// blockIdx = b*8 + sb (adjacent siblings -> drain-safe at any residency).
// LDS: muL fp16 [64][512] = 64 KB resident + stage 8 KB + lmsg 2 KB = 74 KB
// -> 2 blocks/CU (149 KB), grid = exact capacity -> SINGLE generation;
// 16 waves/CU x 128 VGPR = full register pool.
// Sync: 8 arrivals/batch/step (round-9 arity) but 1 generation (round 9 ran
// 2). Per-step model: comp + sync_8 ~ 8 us -> ~170-220 us persist.
// Cross-block: sc1 relaxed partials + per-batch monotonic arrival counter.
// NO fences, NO acquire. Plain launch only (coop ~170 us/replay overhead).
// ---------------------------------------------------------------------------
__global__ __launch_bounds__(PTHREADS, 2) void k_persist(
    const float* __restrict__ scores, const _Float16* __restrict__ MU,
    const _Float16* __restrict__ rho_h, const float* __restrict__ w_ptr,
    const float* __restrict__ alpha_ptr, const float* __restrict__ belt_ptr,
    const float* __restrict__ lra_ptr, const float* __restrict__ lrb_ptr,
    float* __restrict__ rowpart, float* __restrict__ colpart,
    unsigned int* __restrict__ counter, float* __restrict__ Ah) {
  __shared__ _Float16 muL[64][LDIM];  // 64 KB: resident masked usym slab
  __shared__ float stage[4][LDIM];    // 8 KB: cross-wave col-sum staging
  __shared__ float lmsgS[LDIM];       // 2 KB  (total 74 KB -> 2 blocks/CU)

  const int tid = threadIdx.x;
  const int lane = tid & 63;
  const int w = tid >> 6;            // 0..7
  const int b = blockIdx.x >> 3;     // batch
  const int sb = blockIdx.x & 7;     // row slab (64 rows)
  const int wrow = sb * 64 + w * 8;  // global first row of this wave
  const int j0 = lane << 2;          // cols j0..j0+3 and 256+j0..256+j0+3
  const size_t mb = (size_t)b * LDIM * LDIM;

  const float wv = w_ptr[0];
  const float belt = belt_ptr[0];
  const float lra = lra_ptr[0];
  const float lrb = lrb_ptr[0];
  float at = alpha_ptr[0];  // a_t = alpha * lra^sp
  float lrbp = 1.0f;        // lrb^(sp-1) for sp>=1
  float lm_reg = 0.0f;      // Lm[tid]

  const size_t RP = (size_t)BATCH * LDIM;          // rowpart parity stride
  const size_t CP = (size_t)BATCH * SLABS * LDIM;  // colpart parity stride
  unsigned int* const cnt = counter + b * CNT_STRIDE;

  f4 ahv[8][2];
  float colacc[8];

  // __syncthreads() drains vmcnt per wave -> all sc1 partial stores are at
  // the coherence point before tid0's counter add. Spin load RELAXED.
#define ARRIVE_WAIT(tgt)                                                       \
  do {                                                                         \
    __syncthreads();                                                           \
    if (tid == 0) {                                                            \
      __hip_atomic_fetch_add(cnt, 1u, __ATOMIC_RELEASE,                        \
                             __HIP_MEMORY_SCOPE_AGENT);                        \
      while (__hip_atomic_load(cnt, __ATOMIC_RELAXED,                          \
                               __HIP_MEMORY_SCOPE_AGENT) < (tgt))              \
        __builtin_amdgcn_s_sleep(8);                                           \
    }                                                                          \
    __syncthreads();                                                           \
  } while (0)

#define COLREDUCE_STORE(dstp)                                                  \
  do {                                                                         \
    if (w < 4) {                                                               \
      f4 sa = {colacc[0], colacc[1], colacc[2], colacc[3]};                    \
      f4 sbv = {colacc[4], colacc[5], colacc[6], colacc[7]};                   \
      *(f4*)&stage[w][j0] = sa;                                                \
      *(f4*)&stage[w][256 + j0] = sbv;                                         \
    }                                                                          \
    __syncthreads();                                                           \
    if (w >= 4) {                                                              \
      f4 sa = *(f4*)&stage[w - 4][j0];                                         \
      f4 sbv = *(f4*)&stage[w - 4][256 + j0];                                  \
      sa[0] += colacc[0]; sa[1] += colacc[1];                                  \
      sa[2] += colacc[2]; sa[3] += colacc[3];                                  \
      sbv[0] += colacc[4]; sbv[1] += colacc[5];                                \
      sbv[2] += colacc[6]; sbv[3] += colacc[7];                                \
      *(f4*)&stage[w - 4][j0] = sa;                                            \
      *(f4*)&stage[w - 4][256 + j0] = sbv;                                     \
    }                                                                          \
    __syncthreads();                                                           \
    {                                                                          \
      float cs = stage[0][tid] + stage[1][tid] + stage[2][tid] +               \
                 stage[3][tid];                                                \
      st_agent((dstp) + tid, cs);                                              \
    }                                                                          \
  } while (0)

  // ---- P_init: A_hat_0 = scores into VGPRs; MU(fp16) into LDS; partials ----
#pragma unroll
  for (int k = 0; k < 8; k++) colacc[k] = 0.0f;
#pragma unroll
  for (int r = 0; r < 8; r++) {
    const int i = wrow + r;
    const size_t base = mb + (size_t)i * LDIM;
    const f4 s0 = *(const f4*)(scores + base + j0);
    const f4 s1 = *(const f4*)(scores + base + 256 + j0);
    const h4 m0 = *(const h4*)(MU + base + j0);
    const h4 m1 = *(const h4*)(MU + base + 256 + j0);
    ahv[r][0] = s0;
    ahv[r][1] = s1;
    const int lr = (w << 3) + r;
    *(h4*)&muL[lr][j0] = m0;
    *(h4*)&muL[lr][256 + j0] = m1;
    float rowc = 0.0f;
#pragma unroll
    for (int k = 0; k < 4; k++) {
      const float c0v = ((float)m0[k] > MU_THRESH) ? s0[k] : 0.0f;
      const float c1v = ((float)m1[k] > MU_THRESH) ? s1[k] : 0.0f;
      rowc += c0v + c1v;
      colacc[k] += c0v;
      colacc[4 + k] += c1v;
    }
    // full 512-col row lives inside this wave -> rowsum is wave-local
    const float rsum = wave_reduce_sum(rowc);
    if (lane == 0) st_agent(rowpart + (size_t)b * LDIM + i, rsum);
  }
  COLREDUCE_STORE(colpart + ((size_t)b * SLABS + sb) * LDIM);
  ARRIVE_WAIT((unsigned)BPB);

  // ---- 20 steps ----
  for (int sp = 0; sp < NSTEPS; ++sp) {
    const int par = sp & 1;
    // lm phase: identical on all 8 sibling blocks (bit-deterministic).
    {
      const int i = tid;  // PTHREADS == LDIM: one row per thread
      const float rsum = ld_agent(rowpart + (size_t)par * RP + (size_t)b * LDIM + i);
      const float* cb = colpart + (size_t)par * CP + (size_t)b * SLABS * LDIM + i;
      float csum = 0.0f;
#pragma unroll
      for (int s2 = 0; s2 < SLABS; s2++) csum += ld_agent(cb + (size_t)s2 * LDIM);
      const float rd = 0.5f * (rsum + csum) - 1.0f;
      float lm;
      if (sp == 0)
        lm = wv * relu_f(rd);
      else
        lm = lm_reg + belt * lrbp * relu_f(rd);
      lm_reg = lm;
      lmsgS[i] = lm * sign_f(rd);
    }
    __syncthreads();

    const f4 lmja = *(const f4*)&lmsgS[j0];
    const f4 lmjb = *(const f4*)&lmsgS[256 + j0];
    const bool last = (sp == NSTEPS - 1);
    const float rat = at;
#pragma unroll
    for (int k = 0; k < 8; k++) colacc[k] = 0.0f;

#pragma unroll
    for (int r = 0; r < 8; r++) {
      const int i = wrow + r;
      const int lr = (w << 3) + r;
      const float lmi = lmsgS[i];
      const h4 mh0 = *(const h4*)&muL[lr][j0];
      const h4 mh1 = *(const h4*)&muL[lr][256 + j0];
      const h4 rh0 = *(const h4*)(rho_h + (size_t)i * LDIM + j0);
      const h4 rh1 = *(const h4*)(rho_h + (size_t)i * LDIM + 256 + j0);
      float rowc = 0.0f;
#pragma unroll
      for (int k = 0; k < 4; k++) {
        const float mva = (float)mh0[k];
        const bool ma = mva > MU_THRESH;
        const float ga = ma ? (mva - lmi - lmja[k]) : 0.0f;
        const float ua = ahv[r][0][k] * fmaf(rat, ga, 1.0f);
        const float va = fminf(relu_f(fabsf(ua) - (float)rh0[k] * rat), 1.0f);
        ahv[r][0][k] = va;
        const float ca = ma ? va : 0.0f;
        rowc += ca;
        colacc[k] += ca;
        const float mvb = (float)mh1[k];
        const bool mbk = mvb > MU_THRESH;
        const float gb = mbk ? (mvb - lmi - lmjb[k]) : 0.0f;
        const float ub = ahv[r][1][k] * fmaf(rat, gb, 1.0f);
        const float vb = fminf(relu_f(fabsf(ub) - (float)rh1[k] * rat), 1.0f);
        ahv[r][1][k] = vb;
        const float cbv = mbk ? vb : 0.0f;
        rowc += cbv;
        colacc[4 + k] += cbv;
      }
      if (!last) {
        const float rsum = wave_reduce_sum(rowc);
        if (lane == 0)
          st_agent(rowpart + (size_t)(par ^ 1) * RP + (size_t)b * LDIM + i, rsum);
      }
    }
    if (!last) {
      COLREDUCE_STORE(colpart + (size_t)(par ^ 1) * CP +
                      ((size_t)b * SLABS + sb) * LDIM);
      ARRIVE_WAIT((unsigned)BPB * (unsigned)(sp + 2));
    }
    at *= lra;
    if (sp > 0) lrbp *= lrb;
  }

  // ---- write A_hat_20 out (k_final symmetrizes in place) ----
#pragma unroll
  for (int r = 0; r < 8; r++) {
    const size_t base = mb + (size_t)(wrow + r) * LDIM;
    *(f4*)(Ah + base + j0) = ahv[r][0];
    *(f4*)(Ah + base + 256 + j0) = ahv[r][1];
  }
#undef ARRIVE_WAIT
#undef COLREDUCE_STORE
}

// ---------------------------------------------------------------------------
// K_final: in-place A = 0.5*(Ah + Ah^T) .* M over tile pairs (64x64 tiles).
// ---------------------------------------------------------------------------
__global__ __launch_bounds__(NTHREADS) void k_final(float* __restrict__ Ah,
                                                    const float* __restrict__ M) {
  __shared__ float At[64][65];
  __shared__ float Bt[64][65];
  const int b = blockIdx.x / 36;
  int rem = blockIdx.x % 36;
  int ti = 0;
  while (rem >= 8 - ti) {
    rem -= 8 - ti;
    ti++;
  }
  const int tj = ti + rem;
  const int tid = threadIdx.x;
  const int c = tid & 63;
  const int r0 = tid >> 6;
  const size_t mb = (size_t)b * LDIM * LDIM;

#pragma unroll
  for (int k = 0; k < 16; k++) {
    const int r = 4 * k + r0;
    At[r][c] = Ah[mb + (size_t)(ti * 64 + r) * LDIM + tj * 64 + c];
    Bt[r][c] = Ah[mb + (size_t)(tj * 64 + r) * LDIM + ti * 64 + c];
  }
  __syncthreads();
#pragma unroll
  for (int k = 0; k < 16; k++) {
    const int r = 4 * k + r0;
    const size_t idx_ij = mb + (size_t)(ti * 64 + r) * LDIM + tj * 64 + c;
    const float mij = M[idx_ij];
    Ah[idx_ij] = 0.5f * (At[r][c] + Bt[c][r]) * mij;
    if (ti != tj) {
      const size_t idx_ji = mb + (size_t)(tj * 64 + r) * LDIM + ti * 64 + c;
      const float mji = M[idx_ji];
      Ah[idx_ji] = 0.5f * (Bt[r][c] + At[c][r]) * mji;
    }
  }
}

// ---------------------------------------------------------------------------
extern "C" void kernel_launch(void* const* d_in, const int* in_sizes, int n_in,
                              void* d_out, int out_size, void* d_ws,
                              size_t ws_size, hipStream_t stream) {
  const float* scores = (const float*)d_in[0];
  const float* M = (const float*)d_in[1];
  const float* s_p = (const float*)d_in[2];
  const float* w_p = (const float*)d_in[3];
  const float* rho = (const float*)d_in[4];
  const float* alpha_p = (const float*)d_in[5];
  const float* belt_p = (const float*)d_in[6];
  const float* lra_p = (const float*)d_in[7];
  const float* lrb_p = (const float*)d_in[8];
  float* Ah = (float*)d_out;

  char* ws = (char*)d_ws;
  size_t off = 0;
  auto walloc = [&](size_t bytes) -> void* {
    void* p = (void*)(ws + off);
    off += (bytes + 255) & ~(size_t)255;
    return p;
  };
  const size_t NEL = (size_t)BATCH * LDIM * LDIM;
  _Float16* MU = (_Float16*)walloc(NEL * 2);                              // 32 MB
  _Float16* rho_h = (_Float16*)walloc((size_t)LDIM * LDIM * 2);           // 0.5 MB
  float* rowpart = (float*)walloc((size_t)2 * BATCH * LDIM * 4);          // 256 KB
  float* colpart = (float*)walloc((size_t)2 * BATCH * SLABS * LDIM * 4);  // 2 MB
  unsigned int* cnt = (unsigned int*)walloc(BATCH * CNT_STRIDE * 4);      // 4 KB
  (void)in_sizes;
  (void)n_in;
  (void)out_size;
  (void)ws_size;

  k_build<<<dim3(BATCH * 36), dim3(NTHREADS), 0, stream>>>(scores, M, s_p, MU,
                                                           cnt);
  k_rho<<<dim3(LDIM * LDIM / (NTHREADS * 4)), dim3(NTHREADS), 0, stream>>>(
      rho, rho_h);

  // Plain launch only. 512 blocks x 512 thr = exact capacity at 2 blocks/CU
  // (74 KB LDS, 128-VGPR budget via __launch_bounds__(512,2)). Drain-safe at
  // any residency via adjacent per-batch numbering + in-order dispatch.
  k_persist<<<dim3(BATCH * BPB), dim3(PTHREADS), 0, stream>>>(
      scores, MU, rho_h, w_p, alpha_p, belt_p, lra_p, lrb_p, rowpart, colpart,
      cnt, Ah);

  k_final<<<dim3(BATCH * 36), dim3(NTHREADS), 0, stream>>>(Ah, M);
}